// Round 1
// baseline (597.073 us; speedup 1.0000x reference)
//
#include <hip/hip_runtime.h>
#include <hip/hip_bf16.h>

// ---------------------------------------------------------------------------
// MultiHeadAttention: x[4,2048,1024] -> causal MHA (16 heads, d=64) -> out proj
// Strategy: bf16 MFMA (16x16x32) for all matmuls; flash-style attention.
// Layouts: xb [8192][1024] bf16; WT [3072][1024] bf16 (rows = output cols of
// Wq|Wk|Wv); WoT [1024][1024] bf16; Q/K/V [bh=64][2048][64] bf16; ctx
// [8192][1024] bf16 (token-major, head-concat).
// ---------------------------------------------------------------------------

typedef __bf16  bf16x8  __attribute__((ext_vector_type(8)));
typedef float   floatx4 __attribute__((ext_vector_type(4)));

__device__ __forceinline__ unsigned short f2bf(float f) {
    __hip_bfloat16 h = __float2bfloat16(f);
    return *reinterpret_cast<unsigned short*>(&h);
}

// ---------------------------------------------------------------- convert x
__global__ void convert_x(const float* __restrict__ x, unsigned short* __restrict__ xb) {
    int i = (blockIdx.x * 256 + threadIdx.x) * 4;
    float4 v = *(const float4*)(x + i);
    ushort4 o;
    o.x = f2bf(v.x); o.y = f2bf(v.y); o.z = f2bf(v.z); o.w = f2bf(v.w);
    *(ushort4*)(xb + i) = o;
}

// ------------------------------------------------------- transpose weights
// src[k][n] fp32 (1024x1024) -> dst[n][k] bf16. blockIdx.z picks the matrix.
__global__ void transpose_w(const float* __restrict__ Wq, const float* __restrict__ Wk,
                            const float* __restrict__ Wv, const float* __restrict__ Wo,
                            unsigned short* __restrict__ WT, unsigned short* __restrict__ WoT) {
    __shared__ float tile[32][33];
    int mat = blockIdx.z;
    const float* src = (mat == 0) ? Wq : (mat == 1) ? Wk : (mat == 2) ? Wv : Wo;
    unsigned short* dst = (mat < 3) ? WT : WoT;
    int nbase = (mat < 3) ? mat * 1024 : 0;
    int kt = blockIdx.x * 32, nt = blockIdx.y * 32;
    int tx = threadIdx.x, ty = threadIdx.y;
    for (int j = 0; j < 32; j += 8)
        tile[ty + j][tx] = src[(kt + ty + j) * 1024 + nt + tx];
    __syncthreads();
    for (int j = 0; j < 32; j += 8) {
        int n = nt + ty + j;
        dst[(nbase + n) * 1024 + kt + tx] = f2bf(tile[tx][ty + j]);
    }
}

// ---------------------------------------------------------------- GEMM B^T
// C[M,N] = A[M,1024] @ B^T  (B stored [N][1024]).  128x128 tile, BK=64.
// EPI 0: scatter to Q/K/V [bh][seq][64] bf16.  EPI 1: +bias, fp32 out.
template <int EPI>
__global__ __launch_bounds__(256) void gemm_bt(const unsigned short* __restrict__ A,
                                               const unsigned short* __restrict__ B,
                                               unsigned short* __restrict__ Qo,
                                               unsigned short* __restrict__ Ko,
                                               unsigned short* __restrict__ Vo,
                                               const float* __restrict__ bias,
                                               float* __restrict__ Out) {
    constexpr int LDT = 72;  // LDS row stride (elems): 144B -> 2-way conflicts only
    __shared__ __align__(16) unsigned short As[128 * LDT];
    __shared__ __align__(16) unsigned short Bs[128 * LDT];

    int tid = threadIdx.x;
    int lane = tid & 63, w = tid >> 6;
    int wm = w >> 1, wn = w & 1;          // 2x2 waves, each 64x64
    int lm = lane & 15, quad = lane >> 4;
    int m0 = blockIdx.y * 128, n0 = blockIdx.x * 128;

    floatx4 acc[4][4] = {};

    for (int kb = 0; kb < 1024; kb += 64) {
        __syncthreads();
        for (int p = 0; p < 4; ++p) {
            int id = p * 256 + tid;
            int row = id >> 3, cc = (id & 7) * 8;
            *(uint4*)&As[row * LDT + cc] = *(const uint4*)&A[(m0 + row) * 1024 + kb + cc];
            *(uint4*)&Bs[row * LDT + cc] = *(const uint4*)&B[(n0 + row) * 1024 + kb + cc];
        }
        __syncthreads();
        bf16x8 af[2][4], bf[2][4];
        for (int ks = 0; ks < 2; ++ks)
            for (int i = 0; i < 4; ++i) {
                af[ks][i] = *(const bf16x8*)&As[(wm * 64 + i * 16 + lm) * LDT + ks * 32 + quad * 8];
                bf[ks][i] = *(const bf16x8*)&Bs[(wn * 64 + i * 16 + lm) * LDT + ks * 32 + quad * 8];
            }
        for (int mi = 0; mi < 4; ++mi)
            for (int ni = 0; ni < 4; ++ni) {
                acc[mi][ni] = __builtin_amdgcn_mfma_f32_16x16x32_bf16(af[0][mi], bf[0][ni], acc[mi][ni], 0, 0, 0);
                acc[mi][ni] = __builtin_amdgcn_mfma_f32_16x16x32_bf16(af[1][mi], bf[1][ni], acc[mi][ni], 0, 0, 0);
            }
    }

    // C/D layout: col = lane&15, row = quad*4 + r  (m89/m91-verified)
    for (int mi = 0; mi < 4; ++mi)
        for (int ni = 0; ni < 4; ++ni) {
            int gcol = n0 + wn * 64 + ni * 16 + lm;
            if constexpr (EPI == 0) {
                int which = gcol >> 10, hn = gcol & 1023;
                unsigned short* dst = (which == 0) ? Qo : (which == 1) ? Ko : Vo;
                int h = hn >> 6, d = hn & 63;
                for (int r = 0; r < 4; ++r) {
                    int grow = m0 + wm * 64 + mi * 16 + quad * 4 + r;
                    int bb = grow >> 11, s = grow & 2047;
                    dst[(((bb * 16 + h) * 2048) + s) * 64 + d] = f2bf(acc[mi][ni][r]);
                }
            } else {
                float bv = bias[gcol];
                for (int r = 0; r < 4; ++r) {
                    int grow = m0 + wm * 64 + mi * 16 + quad * 4 + r;
                    Out[(size_t)grow * 1024 + gcol] = acc[mi][ni][r] + bv;
                }
            }
        }
}

// ------------------------------------------------------------- attention
// grid (32 qblocks, 64 bh), 256 thr. Wave w: q rows qbase+16w..+15.
// k-blocks of 32; uniform trip count so __syncthreads is legal.
__global__ __launch_bounds__(256) void attn(const unsigned short* __restrict__ Q,
                                            const unsigned short* __restrict__ K,
                                            const unsigned short* __restrict__ V,
                                            unsigned short* __restrict__ ctx) {
    constexpr int LKS = 72;  // K tile row stride
    constexpr int LVS = 56;  // V^T / P row stride (112B, 2-way conflicts only)
    __shared__ __align__(16) unsigned short Ks[32 * LKS];
    __shared__ __align__(16) unsigned short Vt[64 * LVS];
    __shared__ __align__(16) unsigned short Ps[4 * 16 * LVS];

    int tid = threadIdx.x, lane = tid & 63, w = tid >> 6;
    int lm = lane & 15, quad = lane >> 4;
    int bh = blockIdx.y;
    int qbase = blockIdx.x * 64;
    const unsigned short* Qg = Q + (size_t)bh * 2048 * 64;
    const unsigned short* Kg = K + (size_t)bh * 2048 * 64;
    const unsigned short* Vg = V + (size_t)bh * 2048 * 64;

    int qrow = qbase + w * 16 + lm;  // A-frag row for this lane
    bf16x8 aq0 = *(const bf16x8*)&Qg[qrow * 64 + quad * 8];
    bf16x8 aq1 = *(const bf16x8*)&Qg[qrow * 64 + 32 + quad * 8];

    floatx4 O[4] = {};                                   // [dblk], rows quad*4+r
    float mrow[4] = {-INFINITY, -INFINITY, -INFINITY, -INFINITY};
    float lrow[4] = {0.f, 0.f, 0.f, 0.f};
    const float scale = 0.125f;  // 1/sqrt(64)
    int trips = 2 * (blockIdx.x + 1);

    unsigned short* Pw = Ps + w * 16 * LVS;

    for (int t = 0; t < trips; ++t) {
        int kb = t * 32;
        __syncthreads();
        {   // stage K [32][64]->Ks, V [32][64] transposed -> Vt[64][32]
            int row = tid >> 3, cc = (tid & 7) * 8;
            *(uint4*)&Ks[row * LKS + cc] = *(const uint4*)&Kg[(kb + row) * 64 + cc];
            unsigned short vv[8];
            *(uint4*)vv = *(const uint4*)&Vg[(kb + row) * 64 + cc];
            for (int j = 0; j < 8; ++j)
                Vt[(cc + j) * LVS + row] = vv[j];
        }
        __syncthreads();

        floatx4 s0 = {}, s1 = {};
        bf16x8 b0a = *(const bf16x8*)&Ks[lm * LKS + quad * 8];
        bf16x8 b0b = *(const bf16x8*)&Ks[lm * LKS + 32 + quad * 8];
        bf16x8 b1a = *(const bf16x8*)&Ks[(16 + lm) * LKS + quad * 8];
        bf16x8 b1b = *(const bf16x8*)&Ks[(16 + lm) * LKS + 32 + quad * 8];
        s0 = __builtin_amdgcn_mfma_f32_16x16x32_bf16(aq0, b0a, s0, 0, 0, 0);
        s0 = __builtin_amdgcn_mfma_f32_16x16x32_bf16(aq1, b0b, s0, 0, 0, 0);
        s1 = __builtin_amdgcn_mfma_f32_16x16x32_bf16(aq0, b1a, s1, 0, 0, 0);
        s1 = __builtin_amdgcn_mfma_f32_16x16x32_bf16(aq1, b1b, s1, 0, 0, 0);

        int k0 = kb + lm, k1 = kb + 16 + lm;
        for (int r = 0; r < 4; ++r) {
            int q = qbase + w * 16 + quad * 4 + r;
            float v0 = s0[r] * scale; if (k0 > q) v0 = -INFINITY;
            float v1 = s1[r] * scale; if (k1 > q) v1 = -INFINITY;
            float vmax = fmaxf(v0, v1);
            for (int off = 1; off < 16; off <<= 1)
                vmax = fmaxf(vmax, __shfl_xor(vmax, off));
            float mnew = fmaxf(mrow[r], vmax);
            float alpha = __expf(mrow[r] - mnew);
            float p0 = __expf(v0 - mnew);
            float p1 = __expf(v1 - mnew);
            float rs = p0 + p1;
            for (int off = 1; off < 16; off <<= 1)
                rs += __shfl_xor(rs, off);
            lrow[r] = lrow[r] * alpha + rs;
            mrow[r] = mnew;
            for (int dblk = 0; dblk < 4; ++dblk) O[dblk][r] *= alpha;
            Pw[(quad * 4 + r) * LVS + lm]      = f2bf(p0);
            Pw[(quad * 4 + r) * LVS + 16 + lm] = f2bf(p1);
        }
        __syncthreads();  // make P visible (also keeps trips uniform)

        bf16x8 ap = *(const bf16x8*)&Pw[lm * LVS + quad * 8];   // P 16x32 A-frag
        for (int dblk = 0; dblk < 4; ++dblk) {
            bf16x8 bv = *(const bf16x8*)&Vt[(dblk * 16 + lm) * LVS + quad * 8];
            O[dblk] = __builtin_amdgcn_mfma_f32_16x16x32_bf16(ap, bv, O[dblk], 0, 0, 0);
        }
    }

    int b = bh >> 4, h = bh & 15;
    for (int r = 0; r < 4; ++r) {
        int q = qbase + w * 16 + quad * 4 + r;
        float inv = 1.0f / lrow[r];
        for (int dblk = 0; dblk < 4; ++dblk) {
            int d = dblk * 16 + lm;
            ctx[((size_t)(b * 2048 + q)) * 1024 + h * 64 + d] = f2bf(O[dblk][r] * inv);
        }
    }
}

// ---------------------------------------------------------------- launch
extern "C" void kernel_launch(void* const* d_in, const int* in_sizes, int n_in,
                              void* d_out, int out_size, void* d_ws, size_t ws_size,
                              hipStream_t stream) {
    const float* x   = (const float*)d_in[0];
    const float* Wq  = (const float*)d_in[1];
    const float* Wk  = (const float*)d_in[2];
    const float* Wv  = (const float*)d_in[3];
    const float* Wo  = (const float*)d_in[4];
    const float* bo  = (const float*)d_in[5];
    float* out = (float*)d_out;

    char* ws = (char*)d_ws;
    unsigned short* xb  = (unsigned short*)(ws);               // 16 MB
    unsigned short* WT  = (unsigned short*)(ws + 16777216);    // 6 MB
    unsigned short* WoT = (unsigned short*)(ws + 23068672);    // 2 MB
    unsigned short* Qb  = (unsigned short*)(ws + 25165824);    // 16 MB
    unsigned short* Kb  = (unsigned short*)(ws + 41943040);    // 16 MB
    unsigned short* Vb  = (unsigned short*)(ws + 58720256);    // 16 MB
    unsigned short* ctx = (unsigned short*)(ws + 75497472);    // 16 MB  (total 92 MB)

    convert_x<<<8192, 256, 0, stream>>>(x, xb);
    transpose_w<<<dim3(32, 32, 4), dim3(32, 8), 0, stream>>>(Wq, Wk, Wv, Wo, WT, WoT);
    gemm_bt<0><<<dim3(24, 64), 256, 0, stream>>>(xb, WT, Qb, Kb, Vb, nullptr, nullptr);
    attn<<<dim3(32, 64), 256, 0, stream>>>(Qb, Kb, Vb, ctx);
    gemm_bt<1><<<dim3(8, 64), 256, 0, stream>>>(ctx, WoT, nullptr, nullptr, nullptr, bo, out);
}

// Round 2
// 384.296 us; speedup vs baseline: 1.5537x; 1.5537x over previous
//
#include <hip/hip_runtime.h>
#include <hip/hip_bf16.h>
#include <math.h>

// ---------------------------------------------------------------------------
// MultiHeadAttention: x[4,2048,1024] -> causal MHA (16 heads, d=64) -> out proj
// bf16 MFMA (16x16x32) everywhere; flash-style attention with KB=64 k-blocks,
// V stored pre-transposed [bh][d][seq] by the QKV GEMM epilogue, DPP softmax
// reductions (VALU pipe, no ds_swizzle), log2-domain exp.
// ---------------------------------------------------------------------------

typedef __bf16  bf16x8  __attribute__((ext_vector_type(8)));
typedef float   floatx4 __attribute__((ext_vector_type(4)));

__device__ __forceinline__ unsigned short f2bf(float f) {
    __hip_bfloat16 h = __float2bfloat16(f);
    return *reinterpret_cast<unsigned short*>(&h);
}

// DPP row_ror:N within 16-lane rows (full-rate VALU cross-lane)
template <int CTRL>
__device__ __forceinline__ float dppf(float x) {
    int i = __builtin_amdgcn_update_dpp(0, __builtin_bit_cast(int, x), CTRL, 0xF, 0xF, false);
    return __builtin_bit_cast(float, i);
}
__device__ __forceinline__ float rowmax16(float x) {
    x = fmaxf(x, dppf<0x128>(x));  // row_ror:8
    x = fmaxf(x, dppf<0x124>(x));  // row_ror:4
    x = fmaxf(x, dppf<0x122>(x));  // row_ror:2
    x = fmaxf(x, dppf<0x121>(x));  // row_ror:1
    return x;
}
__device__ __forceinline__ float rowsum16(float x) {
    x += dppf<0x128>(x);
    x += dppf<0x124>(x);
    x += dppf<0x122>(x);
    x += dppf<0x121>(x);
    return x;
}

// ---------------------------------------------------------------- convert x
__global__ void convert_x(const float* __restrict__ x, unsigned short* __restrict__ xb) {
    int i = (blockIdx.x * 256 + threadIdx.x) * 4;
    float4 v = *(const float4*)(x + i);
    ushort4 o;
    o.x = f2bf(v.x); o.y = f2bf(v.y); o.z = f2bf(v.z); o.w = f2bf(v.w);
    *(ushort4*)(xb + i) = o;
}

// ------------------------------------------------------- transpose weights
__global__ void transpose_w(const float* __restrict__ Wq, const float* __restrict__ Wk,
                            const float* __restrict__ Wv, const float* __restrict__ Wo,
                            unsigned short* __restrict__ WT, unsigned short* __restrict__ WoT) {
    __shared__ float tile[32][33];
    int mat = blockIdx.z;
    const float* src = (mat == 0) ? Wq : (mat == 1) ? Wk : (mat == 2) ? Wv : Wo;
    unsigned short* dst = (mat < 3) ? WT : WoT;
    int nbase = (mat < 3) ? mat * 1024 : 0;
    int kt = blockIdx.x * 32, nt = blockIdx.y * 32;
    int tx = threadIdx.x, ty = threadIdx.y;
    for (int j = 0; j < 32; j += 8)
        tile[ty + j][tx] = src[(kt + ty + j) * 1024 + nt + tx];
    __syncthreads();
    for (int j = 0; j < 32; j += 8) {
        int n = nt + ty + j;
        dst[(nbase + n) * 1024 + kt + tx] = f2bf(tile[tx][ty + j]);
    }
}

// ---------------------------------------------------------------- GEMM B^T
// C[M,N] = A[M,1024] @ B^T (B stored [N][1024]). 128x128 tile, BK=64.
// EPI 0: scatter Q,K -> [bh][seq][64]; V -> TRANSPOSED [bh][64 d][2048 seq]
//        (packed ushort4 along seq).  EPI 1: +bias, fp32 out.
template <int EPI>
__global__ __launch_bounds__(256) void gemm_bt(const unsigned short* __restrict__ A,
                                               const unsigned short* __restrict__ B,
                                               unsigned short* __restrict__ Qo,
                                               unsigned short* __restrict__ Ko,
                                               unsigned short* __restrict__ Vo,
                                               const float* __restrict__ bias,
                                               float* __restrict__ Out) {
    constexpr int LDT = 72;
    __shared__ __align__(16) unsigned short As[128 * LDT];
    __shared__ __align__(16) unsigned short Bs[128 * LDT];

    int tid = threadIdx.x;
    int lane = tid & 63, w = tid >> 6;
    int wm = w >> 1, wn = w & 1;
    int lm = lane & 15, quad = lane >> 4;
    int m0 = blockIdx.y * 128, n0 = blockIdx.x * 128;

    floatx4 acc[4][4] = {};

    for (int kb = 0; kb < 1024; kb += 64) {
        __syncthreads();
        for (int p = 0; p < 4; ++p) {
            int id = p * 256 + tid;
            int row = id >> 3, cc = (id & 7) * 8;
            *(uint4*)&As[row * LDT + cc] = *(const uint4*)&A[(m0 + row) * 1024 + kb + cc];
            *(uint4*)&Bs[row * LDT + cc] = *(const uint4*)&B[(n0 + row) * 1024 + kb + cc];
        }
        __syncthreads();
        bf16x8 af[2][4], bf[2][4];
        for (int ks = 0; ks < 2; ++ks)
            for (int i = 0; i < 4; ++i) {
                af[ks][i] = *(const bf16x8*)&As[(wm * 64 + i * 16 + lm) * LDT + ks * 32 + quad * 8];
                bf[ks][i] = *(const bf16x8*)&Bs[(wn * 64 + i * 16 + lm) * LDT + ks * 32 + quad * 8];
            }
        for (int mi = 0; mi < 4; ++mi)
            for (int ni = 0; ni < 4; ++ni) {
                acc[mi][ni] = __builtin_amdgcn_mfma_f32_16x16x32_bf16(af[0][mi], bf[0][ni], acc[mi][ni], 0, 0, 0);
                acc[mi][ni] = __builtin_amdgcn_mfma_f32_16x16x32_bf16(af[1][mi], bf[1][ni], acc[mi][ni], 0, 0, 0);
            }
    }

    // C/D layout: col = lane&15, row = quad*4 + r
    for (int mi = 0; mi < 4; ++mi)
        for (int ni = 0; ni < 4; ++ni) {
            int gcol = n0 + wn * 64 + ni * 16 + lm;
            if constexpr (EPI == 0) {
                int which = gcol >> 10, hn = gcol & 1023;
                int h = hn >> 6, d = hn & 63;
                int grow0 = m0 + wm * 64 + mi * 16 + quad * 4;
                int bb = grow0 >> 11, s = grow0 & 2047;
                if (which == 2) {
                    // V transposed: [bh][d][seq], 4 consecutive seq -> ushort4
                    ushort4 pk;
                    pk.x = f2bf(acc[mi][ni][0]); pk.y = f2bf(acc[mi][ni][1]);
                    pk.z = f2bf(acc[mi][ni][2]); pk.w = f2bf(acc[mi][ni][3]);
                    *(ushort4*)&Vo[((size_t)(bb * 16 + h) * 64 + d) * 2048 + s] = pk;
                } else {
                    unsigned short* dst = (which == 0) ? Qo : Ko;
                    for (int r = 0; r < 4; ++r)
                        dst[(((bb * 16 + h) * 2048) + s + r) * 64 + d] = f2bf(acc[mi][ni][r]);
                }
            } else {
                float bv = bias[gcol];
                for (int r = 0; r < 4; ++r) {
                    int grow = m0 + wm * 64 + mi * 16 + quad * 4 + r;
                    Out[(size_t)grow * 1024 + gcol] = acc[mi][ni][r] + bv;
                }
            }
        }
}

// ------------------------------------------------------------- attention
// grid (32 qblocks, 64 bh), 256 thr (4 waves x 16 q-rows). KB=64.
// Vt is pre-transposed [bh][64][2048]. trips = qblock+1 (uniform per block).
__global__ __launch_bounds__(256) void attn(const unsigned short* __restrict__ Q,
                                            const unsigned short* __restrict__ K,
                                            const unsigned short* __restrict__ Vt,
                                            unsigned short* __restrict__ ctx) {
    constexpr int LKS = 72, LVS = 72, LPS = 72;
    __shared__ __align__(16) unsigned short Ks[64 * LKS];
    __shared__ __align__(16) unsigned short Vts[64 * LVS];
    __shared__ __align__(16) unsigned short Ps[4 * 16 * LPS];

    int tid = threadIdx.x, lane = tid & 63, w = tid >> 6;
    int lm = lane & 15, quad = lane >> 4;
    int bh = blockIdx.y, qb = blockIdx.x;
    int qbase = qb * 64;
    const unsigned short* Qg  = Q  + (size_t)bh * 2048 * 64;
    const unsigned short* Kg  = K  + (size_t)bh * 2048 * 64;
    const unsigned short* Vtg = Vt + (size_t)bh * 64 * 2048;

    int qrow = qbase + w * 16 + lm;  // A-frag row (m = lane&15)
    bf16x8 aq0 = *(const bf16x8*)&Qg[qrow * 64 + quad * 8];
    bf16x8 aq1 = *(const bf16x8*)&Qg[qrow * 64 + 32 + quad * 8];

    floatx4 O[4] = {};
    float mrow[4] = {-INFINITY, -INFINITY, -INFINITY, -INFINITY};
    float lrow[4] = {0.f, 0.f, 0.f, 0.f};
    const float scl = 0.125f * 1.44269504f;  // 1/sqrt(64) * log2(e)
    int trips = qb + 1;

    unsigned short* Pw = Ps + w * 16 * LPS;
    int r0 = tid >> 3, c0 = (tid & 7) * 8;  // staging coords (rows 0..31)

    for (int t = 0; t < trips; ++t) {
        int kb = t * 64;
        __syncthreads();
        // stage K tile [64 k][64 d] and V^T tile [64 d][64 k] — all uint4
        *(uint4*)&Ks[r0 * LKS + c0]        = *(const uint4*)&Kg[(kb + r0) * 64 + c0];
        *(uint4*)&Ks[(r0 + 32) * LKS + c0] = *(const uint4*)&Kg[(kb + r0 + 32) * 64 + c0];
        *(uint4*)&Vts[r0 * LVS + c0]        = *(const uint4*)&Vtg[r0 * 2048 + kb + c0];
        *(uint4*)&Vts[(r0 + 32) * LVS + c0] = *(const uint4*)&Vtg[(r0 + 32) * 2048 + kb + c0];
        __syncthreads();

        // S = Q K^T : 16 rows x 64 cols per wave (4 n-chunks)
        floatx4 s[4] = {};
        for (int n = 0; n < 4; ++n) {
            bf16x8 b0 = *(const bf16x8*)&Ks[(n * 16 + lm) * LKS + quad * 8];
            bf16x8 b1 = *(const bf16x8*)&Ks[(n * 16 + lm) * LKS + 32 + quad * 8];
            s[n] = __builtin_amdgcn_mfma_f32_16x16x32_bf16(aq0, b0, s[n], 0, 0, 0);
            s[n] = __builtin_amdgcn_mfma_f32_16x16x32_bf16(aq1, b1, s[n], 0, 0, 0);
        }

        // online softmax (log2 domain), DPP reductions over the 16-lane row
        for (int r = 0; r < 4; ++r) {
            int q = qbase + w * 16 + quad * 4 + r;
            float v[4];
            for (int n = 0; n < 4; ++n) {
                int k = kb + n * 16 + lm;
                v[n] = (k <= q) ? s[n][r] * scl : -INFINITY;
            }
            float vm = fmaxf(fmaxf(v[0], v[1]), fmaxf(v[2], v[3]));
            vm = rowmax16(vm);
            float mnew = fmaxf(mrow[r], vm);
            float alpha = __builtin_amdgcn_exp2f(mrow[r] - mnew);
            float p[4], rs = 0.f;
            for (int n = 0; n < 4; ++n) {
                p[n] = __builtin_amdgcn_exp2f(v[n] - mnew);
                rs += p[n];
            }
            rs = rowsum16(rs);
            lrow[r] = lrow[r] * alpha + rs;
            mrow[r] = mnew;
            for (int dblk = 0; dblk < 4; ++dblk) O[dblk][r] *= alpha;
            for (int n = 0; n < 4; ++n)
                Pw[(quad * 4 + r) * LPS + n * 16 + lm] = f2bf(p[n]);
        }
        __syncthreads();

        // O += P V : P 16x64 (2 A-frags), V^T rows are d
        bf16x8 ap0 = *(const bf16x8*)&Pw[lm * LPS + quad * 8];
        bf16x8 ap1 = *(const bf16x8*)&Pw[lm * LPS + 32 + quad * 8];
        for (int dblk = 0; dblk < 4; ++dblk) {
            bf16x8 bv0 = *(const bf16x8*)&Vts[(dblk * 16 + lm) * LVS + quad * 8];
            bf16x8 bv1 = *(const bf16x8*)&Vts[(dblk * 16 + lm) * LVS + 32 + quad * 8];
            O[dblk] = __builtin_amdgcn_mfma_f32_16x16x32_bf16(ap0, bv0, O[dblk], 0, 0, 0);
            O[dblk] = __builtin_amdgcn_mfma_f32_16x16x32_bf16(ap1, bv1, O[dblk], 0, 0, 0);
        }
    }

    int b = bh >> 4, h = bh & 15;
    for (int r = 0; r < 4; ++r) {
        int q = qbase + w * 16 + quad * 4 + r;
        float inv = 1.0f / lrow[r];
        for (int dblk = 0; dblk < 4; ++dblk) {
            int d = dblk * 16 + lm;
            ctx[((size_t)(b * 2048 + q)) * 1024 + h * 64 + d] = f2bf(O[dblk][r] * inv);
        }
    }
}

// ---------------------------------------------------------------- launch
extern "C" void kernel_launch(void* const* d_in, const int* in_sizes, int n_in,
                              void* d_out, int out_size, void* d_ws, size_t ws_size,
                              hipStream_t stream) {
    const float* x   = (const float*)d_in[0];
    const float* Wq  = (const float*)d_in[1];
    const float* Wk  = (const float*)d_in[2];
    const float* Wv  = (const float*)d_in[3];
    const float* Wo  = (const float*)d_in[4];
    const float* bo  = (const float*)d_in[5];
    float* out = (float*)d_out;

    char* ws = (char*)d_ws;
    unsigned short* xb  = (unsigned short*)(ws);               // 16 MB
    unsigned short* WT  = (unsigned short*)(ws + 16777216);    // 6 MB
    unsigned short* WoT = (unsigned short*)(ws + 23068672);    // 2 MB
    unsigned short* Qb  = (unsigned short*)(ws + 25165824);    // 16 MB
    unsigned short* Kb  = (unsigned short*)(ws + 41943040);    // 16 MB
    unsigned short* Vtb = (unsigned short*)(ws + 58720256);    // 16 MB (transposed)
    unsigned short* ctx = (unsigned short*)(ws + 75497472);    // 16 MB

    convert_x<<<8192, 256, 0, stream>>>(x, xb);
    transpose_w<<<dim3(32, 32, 4), dim3(32, 8), 0, stream>>>(Wq, Wk, Wv, Wo, WT, WoT);
    gemm_bt<0><<<dim3(24, 64), 256, 0, stream>>>(xb, WT, Qb, Kb, Vtb, nullptr, nullptr);
    attn<<<dim3(32, 64), 256, 0, stream>>>(Qb, Kb, Vtb, ctx);
    gemm_bt<1><<<dim3(8, 64), 256, 0, stream>>>(ctx, WoT, nullptr, nullptr, nullptr, bo, out);
}